// Round 7
// baseline (1013.033 us; speedup 1.0000x reference)
//
#include <hip/hip_runtime.h>
#include <hip/hip_cooperative_groups.h>
#include <hip/hip_fp16.h>

namespace cg = cooperative_groups;

#define N_NODES 100000
#define N_EDGES 1600000
#define MSG 16
#define HID 16
#define NT 8
#define NC 32
#define PREP_N 800000       // N*HID/2 packed half2 words == N*MSG/2 m2 words
#define A2_WORDS 1024       // NT*MSG*HID/2 packed half2 words (4 KB)
#define GRID_BLKS 1024      // 4 blocks/CU on 256 CUs; __launch_bounds__(256,4)

typedef _Float16 v2h __attribute__((ext_vector_type(2)));

union H2U {
    v2h h;
    unsigned int u;
};

__device__ __forceinline__ float dot2acc(unsigned int a, unsigned int b, float acc) {
    H2U x, y;
    x.u = a; y.u = b;
#if __has_builtin(__builtin_amdgcn_fdot2)
    return __builtin_amdgcn_fdot2(x.h, y.h, acc, false);
#else
    return acc + (float)x.h[0] * (float)y.h[0] + (float)x.h[1] * (float)y.h[1];
#endif
}

__device__ __forceinline__ float fast_sigmoid(float x) {
    return 1.f / (1.f + __expf(-x));
}
__device__ __forceinline__ float fast_tanh(float x) {
    return 2.f / (1.f + __expf(-2.f * x)) - 1.f;
}

// ---------------------------------------------------------------------------
// Phase bodies (shared between the cooperative kernel and fallback kernels)
// ---------------------------------------------------------------------------
__device__ __forceinline__ void prep_body(
    int tid, int nthreads,
    const float* __restrict__ feat, const float* __restrict__ edge_table,
    unsigned int* __restrict__ feat16, unsigned int* __restrict__ m2,
    unsigned int* __restrict__ A2) {
    for (int i = tid; i < PREP_N; i += nthreads) {
        float2 f = reinterpret_cast<const float2*>(feat)[i];
        H2U p;
        p.h[0] = (_Float16)f.x;
        p.h[1] = (_Float16)f.y;
        feat16[i] = p.u;
        m2[i] = 0u;
    }
    for (int i = tid; i < A2_WORDS; i += nthreads) {
        float2 f = reinterpret_cast<const float2*>(edge_table)[i];
        H2U p;
        p.h[0] = (_Float16)f.x;
        p.h[1] = (_Float16)f.y;
        A2[i] = p.u;
    }
}

__device__ __forceinline__ void edge_body(
    int tid, int nthreads,
    const int* __restrict__ src, const int* __restrict__ dst,
    const int* __restrict__ etype,
    const unsigned int* __restrict__ feat16,
    const unsigned int* __restrict__ A2,
    unsigned int* __restrict__ m2) {
    int c = tid & 7;                       // output pair (2c, 2c+1)
    int estride = nthreads >> 3;
    for (int e = tid >> 3; e < N_EDGES; e += estride) {
        int s = src[e];
        int t = etype[e];
        // full h_src: 32 B (8 packed half2 words), L2-resident 3.2 MB mirror
        const uint4* hp = reinterpret_cast<const uint4*>(feat16 + (size_t)s * 8);
        uint4 h0 = hp[0], h1 = hp[1];
        // A rows 2c and 2c+1: 16 consecutive packed words, 4 KB L1-resident
        const uint4* ap = reinterpret_cast<const uint4*>(A2 + t * 128 + c * 16);
        uint4 a0 = ap[0], a1 = ap[1], a2 = ap[2], a3 = ap[3];

        float r0 = 0.f, r1 = 0.f;
        r0 = dot2acc(h0.x, a0.x, r0); r0 = dot2acc(h0.y, a0.y, r0);
        r0 = dot2acc(h0.z, a0.z, r0); r0 = dot2acc(h0.w, a0.w, r0);
        r0 = dot2acc(h1.x, a1.x, r0); r0 = dot2acc(h1.y, a1.y, r0);
        r0 = dot2acc(h1.z, a1.z, r0); r0 = dot2acc(h1.w, a1.w, r0);
        r1 = dot2acc(h0.x, a2.x, r1); r1 = dot2acc(h0.y, a2.y, r1);
        r1 = dot2acc(h0.z, a2.z, r1); r1 = dot2acc(h0.w, a2.w, r1);
        r1 = dot2acc(h1.x, a3.x, r1); r1 = dot2acc(h1.y, a3.y, r1);
        r1 = dot2acc(h1.z, a3.z, r1); r1 = dot2acc(h1.w, a3.w, r1);

        int d = dst[e];
        H2U p;
        p.h[0] = (_Float16)r0;
        p.h[1] = (_Float16)r1;
#if __has_builtin(__builtin_amdgcn_global_atomic_fadd_v2f16)
        __builtin_amdgcn_global_atomic_fadd_v2f16(
            reinterpret_cast<v2h*>(m2 + (size_t)d * 8 + c), p.h);
#endif
    }
}

__device__ __forceinline__ void node_body(
    int tid, int nthreads,
    const float* __restrict__ feat, const unsigned int* __restrict__ m2,
    const float* __restrict__ W_ih, const float* __restrict__ W_hh,
    const float* __restrict__ b_ih, const float* __restrict__ b_hh,
    const float* __restrict__ W_out, const float* __restrict__ b_out,
    float* __restrict__ out) {
    for (int n = tid; n < N_NODES; n += nthreads) {
        float mv[MSG], h[HID];
        const uint4* mu = reinterpret_cast<const uint4*>(m2 + (size_t)n * 8);
        uint4 a = mu[0], b = mu[1];
        unsigned int w[8] = {a.x, a.y, a.z, a.w, b.x, b.y, b.z, b.w};
        #pragma unroll
        for (int i = 0; i < 8; ++i) {
            H2U hh;
            hh.u = w[i];
            mv[2 * i]     = (float)hh.h[0];
            mv[2 * i + 1] = (float)hh.h[1];
        }
        const float4* f4 = reinterpret_cast<const float4*>(feat + (size_t)n * HID);
        #pragma unroll
        for (int q = 0; q < 4; ++q) {
            float4 v = f4[q];
            h[q * 4 + 0] = v.x; h[q * 4 + 1] = v.y;
            h[q * 4 + 2] = v.z; h[q * 4 + 3] = v.w;
        }

        float srz[2 * HID];
        for (int g = 0; g < 2 * HID; ++g) {
            float ai = 0.f, ah = 0.f;
            const float* wi = W_ih + g * MSG;
            const float* wh = W_hh + g * HID;
            #pragma unroll
            for (int k = 0; k < HID; ++k) {
                ai += wi[k] * mv[k];
                ah += wh[k] * h[k];
            }
            srz[g] = ai + ah + b_ih[g] + b_hh[g];
        }
        float i_n[HID], h_n[HID];
        #pragma unroll
        for (int j = 0; j < HID; ++j) {
            int g = 2 * HID + j;
            float ai = b_ih[g], ah = b_hh[g];
            const float* wi = W_ih + g * MSG;
            const float* wh = W_hh + g * HID;
            #pragma unroll
            for (int k = 0; k < HID; ++k) {
                ai += wi[k] * mv[k];
                ah += wh[k] * h[k];
            }
            i_n[j] = ai;
            h_n[j] = ah;
        }

        float hn[HID];
        #pragma unroll
        for (int j = 0; j < HID; ++j) {
            float r = fast_sigmoid(srz[j]);
            float z = fast_sigmoid(srz[HID + j]);
            float nn = fast_tanh(i_n[j] + r * h_n[j]);
            hn[j] = (1.f - z) * nn + z * h[j];
        }

        float4* op = reinterpret_cast<float4*>(out + (size_t)n * NC);
        #pragma unroll
        for (int c4 = 0; c4 < NC / 4; ++c4) {
            float4 o;
            float* oo = &o.x;
            #pragma unroll
            for (int cc = 0; cc < 4; ++cc) {
                int cI = c4 * 4 + cc;
                float acc = b_out[cI];
                const float* wo = W_out + cI * HID;
                #pragma unroll
                for (int k = 0; k < HID; ++k) acc += wo[k] * hn[k];
                oo[cc] = acc;
            }
            op[c4] = o;
        }
    }
}

// ---------------------------------------------------------------------------
// Single cooperative kernel: prep -> sync -> edges -> sync -> GRU+out
// ---------------------------------------------------------------------------
__global__ __launch_bounds__(256, 4) void ggnn_fused(
    const float* feat, const int* src, const int* dst, const int* etype,
    const float* edge_table, const float* W_ih, const float* W_hh,
    const float* b_ih, const float* b_hh, const float* W_out,
    const float* b_out, float* out,
    unsigned int* m2, unsigned int* feat16, unsigned int* A2) {
    cg::grid_group grid = cg::this_grid();
    int tid = blockIdx.x * 256 + threadIdx.x;
    int nthreads = gridDim.x * 256;

    prep_body(tid, nthreads, feat, edge_table, feat16, m2, A2);
    grid.sync();
    edge_body(tid, nthreads, src, dst, etype, feat16, A2, m2);
    grid.sync();
    node_body(tid, nthreads, feat, m2, W_ih, W_hh, b_ih, b_hh, W_out, b_out, out);
}

// ---------------------------------------------------------------------------
// Fallback kernels (used only if cooperative launch is unavailable)
// ---------------------------------------------------------------------------
__global__ __launch_bounds__(256) void ggnn_prep_k(
    const float* feat, const float* edge_table,
    unsigned int* feat16, unsigned int* m2, unsigned int* A2) {
    prep_body(blockIdx.x * 256 + threadIdx.x, gridDim.x * 256,
              feat, edge_table, feat16, m2, A2);
}
__global__ __launch_bounds__(256) void ggnn_edge_k(
    const int* src, const int* dst, const int* etype,
    const unsigned int* feat16, const unsigned int* A2, unsigned int* m2) {
    edge_body(blockIdx.x * 256 + threadIdx.x, gridDim.x * 256,
              src, dst, etype, feat16, A2, m2);
}
__global__ __launch_bounds__(256) void ggnn_node_k(
    const float* feat, const unsigned int* m2,
    const float* W_ih, const float* W_hh, const float* b_ih,
    const float* b_hh, const float* W_out, const float* b_out, float* out) {
    node_body(blockIdx.x * 256 + threadIdx.x, gridDim.x * 256,
              feat, m2, W_ih, W_hh, b_ih, b_hh, W_out, b_out, out);
}

extern "C" void kernel_launch(void* const* d_in, const int* in_sizes, int n_in,
                              void* d_out, int out_size, void* d_ws, size_t ws_size,
                              hipStream_t stream) {
    const float* feat       = (const float*)d_in[0];
    const int*   src        = (const int*)d_in[1];
    const int*   dst        = (const int*)d_in[2];
    const int*   etype      = (const int*)d_in[3];
    const float* edge_table = (const float*)d_in[4];
    const float* W_ih       = (const float*)d_in[5];
    const float* W_hh       = (const float*)d_in[6];
    const float* b_ih       = (const float*)d_in[7];
    const float* b_hh       = (const float*)d_in[8];
    const float* W_out      = (const float*)d_in[9];
    const float* b_out      = (const float*)d_in[10];
    float* out = (float*)d_out;

    // workspace: m2 [800K words], feat16 [800K words], A2 [1K words]
    unsigned int* m2     = (unsigned int*)d_ws;
    unsigned int* feat16 = m2 + PREP_N;
    unsigned int* A2     = feat16 + PREP_N;

    void* args[] = {
        (void*)&feat, (void*)&src, (void*)&dst, (void*)&etype,
        (void*)&edge_table, (void*)&W_ih, (void*)&W_hh, (void*)&b_ih,
        (void*)&b_hh, (void*)&W_out, (void*)&b_out, (void*)&out,
        (void*)&m2, (void*)&feat16, (void*)&A2,
    };
    hipError_t err = hipLaunchCooperativeKernel(
        reinterpret_cast<void*>(ggnn_fused), dim3(GRID_BLKS), dim3(256),
        args, 0, stream);
    if (err != hipSuccess) {
        // fallback: 3 plain dispatches (same math, global sync between)
        ggnn_prep_k<<<3125, 256, 0, stream>>>(feat, edge_table, feat16, m2, A2);
        ggnn_edge_k<<<GRID_BLKS, 256, 0, stream>>>(src, dst, etype, feat16, A2, m2);
        ggnn_node_k<<<391, 256, 0, stream>>>(feat, m2, W_ih, W_hh, b_ih, b_hh,
                                             W_out, b_out, out);
    }
}

// Round 8
// 201.211 us; speedup vs baseline: 5.0347x; 5.0347x over previous
//
#include <hip/hip_runtime.h>
#include <hip/hip_fp16.h>

#define N_NODES 100000
#define N_EDGES 1600000
#define MSG 16
#define HID 16
#define NT 8
#define NC 32
#define PREP_N 800000       // N*HID/2 packed half2 words == N*MSG/2 m2 words
#define A2_WORDS 1024       // NT*MSG*HID/2 packed half2 words (4 KB)

typedef _Float16 v2h __attribute__((ext_vector_type(2)));

union H2U {
    v2h h;
    unsigned int u;
};

__device__ __forceinline__ float dot2acc(unsigned int a, unsigned int b, float acc) {
    H2U x, y;
    x.u = a; y.u = b;
#if __has_builtin(__builtin_amdgcn_fdot2)
    return __builtin_amdgcn_fdot2(x.h, y.h, acc, false);
#else
    return acc + (float)x.h[0] * (float)y.h[0] + (float)x.h[1] * (float)y.h[1];
#endif
}

__device__ __forceinline__ float fast_sigmoid(float x) {
    return 1.f / (1.f + __expf(-x));
}
__device__ __forceinline__ float fast_tanh(float x) {
    return 2.f / (1.f + __expf(-2.f * x)) - 1.f;
}

// ---------------------------------------------------------------------------
// Prep: feat f32 -> packed fp16 mirror; zero m2; pack edge_table to fp16.
// ---------------------------------------------------------------------------
__global__ __launch_bounds__(256) void ggnn_prep(
    const float* __restrict__ feat,
    const float* __restrict__ edge_table,
    unsigned int* __restrict__ feat16,
    unsigned int* __restrict__ m2,
    unsigned int* __restrict__ A2) {
    int i = blockIdx.x * 256 + threadIdx.x;
    if (i < PREP_N) {
        float2 f = reinterpret_cast<const float2*>(feat)[i];
        H2U p;
        p.h[0] = (_Float16)f.x;
        p.h[1] = (_Float16)f.y;
        feat16[i] = p.u;
        m2[i] = 0u;
    }
    if (i < A2_WORDS) {
        float2 f = reinterpret_cast<const float2*>(edge_table)[i];
        H2U p;
        p.h[0] = (_Float16)f.x;
        p.h[1] = (_Float16)f.y;
        A2[i] = p.u;
    }
}

// ---------------------------------------------------------------------------
// Edge kernel: 8 threads per edge, thread c computes output pair (2c,2c+1)
// via v_dot2_f32_f16. h_src from the 3.2 MB fp16 mirror (L2-resident);
// A rows from the 4 KB packed table (L1-resident). Zero LDS, zero shuffles.
// One packed fp16 fire-and-forget atomic per thread (12.8M total).
// ---------------------------------------------------------------------------
__global__ __launch_bounds__(256) void ggnn_edge(
    const int* __restrict__ src,
    const int* __restrict__ dst,
    const int* __restrict__ etype,
    const unsigned int* __restrict__ feat16,
    const unsigned int* __restrict__ A2,
    unsigned int* __restrict__ m2) {
    int tid = blockIdx.x * 256 + threadIdx.x;
    int e = tid >> 3;
    if (e >= N_EDGES) return;
    int c = tid & 7;

    int s = src[e];
    int t = etype[e];
    const uint4* hp = reinterpret_cast<const uint4*>(feat16 + (size_t)s * 8);
    uint4 h0 = hp[0], h1 = hp[1];
    const uint4* ap = reinterpret_cast<const uint4*>(A2 + t * 128 + c * 16);
    uint4 a0 = ap[0], a1 = ap[1], a2 = ap[2], a3 = ap[3];

    float r0 = 0.f, r1 = 0.f;
    r0 = dot2acc(h0.x, a0.x, r0); r0 = dot2acc(h0.y, a0.y, r0);
    r0 = dot2acc(h0.z, a0.z, r0); r0 = dot2acc(h0.w, a0.w, r0);
    r0 = dot2acc(h1.x, a1.x, r0); r0 = dot2acc(h1.y, a1.y, r0);
    r0 = dot2acc(h1.z, a1.z, r0); r0 = dot2acc(h1.w, a1.w, r0);
    r1 = dot2acc(h0.x, a2.x, r1); r1 = dot2acc(h0.y, a2.y, r1);
    r1 = dot2acc(h0.z, a2.z, r1); r1 = dot2acc(h0.w, a2.w, r1);
    r1 = dot2acc(h1.x, a3.x, r1); r1 = dot2acc(h1.y, a3.y, r1);
    r1 = dot2acc(h1.z, a3.z, r1); r1 = dot2acc(h1.w, a3.w, r1);

    int d = dst[e];
    H2U p;
    p.h[0] = (_Float16)r0;
    p.h[1] = (_Float16)r1;
#if __has_builtin(__builtin_amdgcn_global_atomic_fadd_v2f16)
    __builtin_amdgcn_global_atomic_fadd_v2f16(
        reinterpret_cast<v2h*>(m2 + (size_t)d * 8 + c), p.h);
#endif
}

// ---------------------------------------------------------------------------
// Node kernel: GRU cell + output projection. One thread per node; weights
// are wave-uniform -> scalar loads.
// ---------------------------------------------------------------------------
__global__ __launch_bounds__(256) void ggnn_node(
    const float* __restrict__ feat,
    const unsigned int* __restrict__ m2,
    const float* __restrict__ W_ih,
    const float* __restrict__ W_hh,
    const float* __restrict__ b_ih,
    const float* __restrict__ b_hh,
    const float* __restrict__ W_out,
    const float* __restrict__ b_out,
    float* __restrict__ out) {
    int n = blockIdx.x * 256 + threadIdx.x;
    if (n >= N_NODES) return;

    float mv[MSG], h[HID];
    {
        const uint4* mu = reinterpret_cast<const uint4*>(m2 + (size_t)n * 8);
        uint4 a = mu[0], b = mu[1];
        unsigned int w[8] = {a.x, a.y, a.z, a.w, b.x, b.y, b.z, b.w};
        #pragma unroll
        for (int i = 0; i < 8; ++i) {
            H2U hh;
            hh.u = w[i];
            mv[2 * i]     = (float)hh.h[0];
            mv[2 * i + 1] = (float)hh.h[1];
        }
        const float4* f4 = reinterpret_cast<const float4*>(feat + (size_t)n * HID);
        #pragma unroll
        for (int q = 0; q < 4; ++q) {
            float4 v = f4[q];
            h[q * 4 + 0] = v.x; h[q * 4 + 1] = v.y;
            h[q * 4 + 2] = v.z; h[q * 4 + 3] = v.w;
        }
    }

    float srz[2 * HID];
    for (int g = 0; g < 2 * HID; ++g) {
        float ai = 0.f, ah = 0.f;
        const float* wi = W_ih + g * MSG;
        const float* wh = W_hh + g * HID;
        #pragma unroll
        for (int k = 0; k < HID; ++k) {
            ai += wi[k] * mv[k];
            ah += wh[k] * h[k];
        }
        srz[g] = ai + ah + b_ih[g] + b_hh[g];
    }
    float i_n[HID], h_n[HID];
    #pragma unroll
    for (int j = 0; j < HID; ++j) {
        int g = 2 * HID + j;
        float ai = b_ih[g], ah = b_hh[g];
        const float* wi = W_ih + g * MSG;
        const float* wh = W_hh + g * HID;
        #pragma unroll
        for (int k = 0; k < HID; ++k) {
            ai += wi[k] * mv[k];
            ah += wh[k] * h[k];
        }
        i_n[j] = ai;
        h_n[j] = ah;
    }

    float hn[HID];
    #pragma unroll
    for (int j = 0; j < HID; ++j) {
        float r = fast_sigmoid(srz[j]);
        float z = fast_sigmoid(srz[HID + j]);
        float nn = fast_tanh(i_n[j] + r * h_n[j]);
        hn[j] = (1.f - z) * nn + z * h[j];
    }

    float4* op = reinterpret_cast<float4*>(out + (size_t)n * NC);
    #pragma unroll
    for (int c4 = 0; c4 < NC / 4; ++c4) {
        float4 o;
        float* oo = &o.x;
        #pragma unroll
        for (int cc = 0; cc < 4; ++cc) {
            int c = c4 * 4 + cc;
            float acc = b_out[c];
            const float* wo = W_out + c * HID;
            #pragma unroll
            for (int k = 0; k < HID; ++k) acc += wo[k] * hn[k];
            oo[cc] = acc;
        }
        op[c4] = o;
    }
}

extern "C" void kernel_launch(void* const* d_in, const int* in_sizes, int n_in,
                              void* d_out, int out_size, void* d_ws, size_t ws_size,
                              hipStream_t stream) {
    const float* feat       = (const float*)d_in[0];
    const int*   src        = (const int*)d_in[1];
    const int*   dst        = (const int*)d_in[2];
    const int*   etype      = (const int*)d_in[3];
    const float* edge_table = (const float*)d_in[4];
    const float* W_ih       = (const float*)d_in[5];
    const float* W_hh       = (const float*)d_in[6];
    const float* b_ih       = (const float*)d_in[7];
    const float* b_hh       = (const float*)d_in[8];
    const float* W_out      = (const float*)d_in[9];
    const float* b_out      = (const float*)d_in[10];
    float* out = (float*)d_out;

    // workspace: m2 [800K words], feat16 [800K words], A2 [1K words]
    unsigned int* m2     = (unsigned int*)d_ws;
    unsigned int* feat16 = m2 + PREP_N;
    unsigned int* A2     = feat16 + PREP_N;

    int pblocks = (PREP_N + 255) / 256;                  // 3125
    ggnn_prep<<<pblocks, 256, 0, stream>>>(feat, edge_table, feat16, m2, A2);

    long long ethreads = (long long)N_EDGES * 8;         // 12.8M
    int eblocks = (int)((ethreads + 255) / 256);         // 50000
    ggnn_edge<<<eblocks, 256, 0, stream>>>(src, dst, etype, feat16, A2, m2);

    int nblocks = (N_NODES + 255) / 256;                 // 391
    ggnn_node<<<nblocks, 256, 0, stream>>>(feat, m2, W_ih, W_hh, b_ih, b_hh,
                                           W_out, b_out, out);
}